// Round 11
// baseline (133.620 us; speedup 1.0000x reference)
//
#include <hip/hip_runtime.h>

#define CCH 32
#define BCH 6
#define HH  180
#define WW  320
#define NN  (HH*WW)             // 57600
#define BATCH 32
#define RPC 8                    // rows per chunk
#define CHUNKS ((HH + RPC - 1)/RPC)   // 23 (last chunk: 4 rows)
#define THREADS 640              // 10 waves; 4 px per thread

typedef float f32x2 __attribute__((ext_vector_type(2)));
typedef float f32x4 __attribute__((ext_vector_type(4)));

// ---- kernel A: se_r[c][p] = se[c][walk-strip(p)] + b_deflat[c]  (raster order)
__global__ __launch_bounds__(256) void permute_se(
    const float* __restrict__ se, const int* __restrict__ unwalk,
    const float* __restrict__ b_deflat, float* __restrict__ se_r)
{
    const int p = (blockIdx.x * 256 + threadIdx.x) * 4;
    if (p >= NN) return;
    const int i  = p / WW;
    const int j  = p % WW;                      // multiple of 4
    const int nb = unwalk[(i & ~1)*WW + j];     // 2x4-block base rank
    const int n2 = nb + 2*(i & 1);
    const int c0 = blockIdx.y * (CCH/4);        // 8 channels per block.y
    #pragma unroll
    for (int cc = 0; cc < CCH/4; ++cc) {
        const int c = c0 + cc;
        const f32x2 a  = *reinterpret_cast<const f32x2*>(se + (size_t)c*NN + n2);
        const f32x2 b2 = *reinterpret_cast<const f32x2*>(se + (size_t)c*NN + n2 + 4);
        const float bd = b_deflat[c];
        f32x4 v; v.x = a.x + bd; v.y = a.y + bd; v.z = b2.x + bd; v.w = b2.y + bd;
        *reinterpret_cast<f32x4*>(se_r + (size_t)c*NN + p) = v;
    }
}

// ---- K1: flat = W_f @ latent + b_f.  Read-dominated (236R : 44W).
__global__ __launch_bounds__(THREADS) void flatten_k(
    const float* __restrict__ latent, const float* __restrict__ w_flat,
    const float* __restrict__ b_flat, const int* __restrict__ unwalk,
    float* __restrict__ flat_out)
{
    __shared__ float s_wf[BCH*CCH];
    __shared__ float s_bf[BCH];
    const int t  = threadIdx.x;
    const int bx = blockIdx.x;
    const int r  = bx >> 5;            // chunk (b-inner: L2 sharing of unwalk)
    const int b  = bx & 31;

    if (t < BCH*CCH) s_wf[t] = w_flat[t];
    if (t < BCH)     s_bf[t] = b_flat[t];
    __syncthreads();

    const int i  = RPC*r + t/80;
    if (i >= HH) return;
    const int j  = 4*(t%80);
    const int p  = i*WW + j;

    const int nb = unwalk[(i & ~1)*WW + j];
    const int n2 = nb + 2*(i & 1);

    const float* latb = latent + (size_t)b * (CCH*NN) + p;

    float acc[BCH][4];
    #pragma unroll
    for (int o = 0; o < BCH; ++o) {
        const float bo = s_bf[o];
        acc[o][0] = bo; acc[o][1] = bo; acc[o][2] = bo; acc[o][3] = bo;
    }
    #pragma unroll 8
    for (int c = 0; c < CCH; ++c) {
        const f32x4 x = __builtin_nontemporal_load(
            reinterpret_cast<const f32x4*>(latb + (size_t)c*NN));
        #pragma unroll
        for (int o = 0; o < BCH; ++o) {
            const float w = s_wf[o*CCH + c];
            acc[o][0] += w*x.x; acc[o][1] += w*x.y;
            acc[o][2] += w*x.z; acc[o][3] += w*x.w;
        }
    }
    float* fb = flat_out + (size_t)b * (BCH*NN) + n2;
    #pragma unroll
    for (int o = 0; o < BCH; ++o) {
        f32x2 lo; lo.x = acc[o][0]; lo.y = acc[o][1];
        f32x2 hi; hi.x = acc[o][2]; hi.y = acc[o][3];
        *reinterpret_cast<f32x2*>(fb + (size_t)o*NN)     = lo;
        *reinterpret_cast<f32x2*>(fb + (size_t)o*NN + 4) = hi;
    }
}

// ---- K2: recon = W_d @ flat + se_r.  Write-dominated (236W; flat/se_r cached).
template<int SE_RASTER>
__global__ __launch_bounds__(THREADS) void deflatten_k(
    const float* __restrict__ flat_in, const float* __restrict__ w_deflat,
    const float* __restrict__ b_deflat, const float* __restrict__ se,
    const int* __restrict__ unwalk, float* __restrict__ recon)
{
    __shared__ float s_wd[CCH*BCH];
    __shared__ float s_bd[CCH];
    const int t  = threadIdx.x;
    const int bx = blockIdx.x;
    const int r  = bx >> 5;            // b-inner: flat/se_r windows shared in L2
    const int b  = bx & 31;

    if (t < BCH*CCH) s_wd[t] = w_deflat[t];
    if (t < CCH)     s_bd[t] = b_deflat[t];
    __syncthreads();

    const int i  = RPC*r + t/80;
    if (i >= HH) return;
    const int j  = 4*(t%80);
    const int p  = i*WW + j;

    const int nb = unwalk[(i & ~1)*WW + j];
    const int n2 = nb + 2*(i & 1);

    // load this strip's flat values (L2/L3-hot: written by K1 just before)
    float fv[BCH][4];
    const float* fb = flat_in + (size_t)b * (BCH*NN) + n2;
    #pragma unroll
    for (int o = 0; o < BCH; ++o) {
        const f32x2 lo = *reinterpret_cast<const f32x2*>(fb + (size_t)o*NN);
        const f32x2 hi = *reinterpret_cast<const f32x2*>(fb + (size_t)o*NN + 4);
        fv[o][0] = lo.x; fv[o][1] = lo.y; fv[o][2] = hi.x; fv[o][3] = hi.y;
    }

    float* reconb = recon + (size_t)b * (CCH*NN) + p;
    #pragma unroll 8
    for (int c = 0; c < CCH; ++c) {
        float y0, y1, y2, y3;
        if (SE_RASTER) {
            const f32x4 s4 = *reinterpret_cast<const f32x4*>(se + (size_t)c*NN + p);
            y0 = s4.x; y1 = s4.y; y2 = s4.z; y3 = s4.w;   // bias pre-folded
        } else {
            const f32x2 a  = *reinterpret_cast<const f32x2*>(se + (size_t)c*NN + n2);
            const f32x2 bq = *reinterpret_cast<const f32x2*>(se + (size_t)c*NN + n2 + 4);
            const float bd = s_bd[c];
            y0 = bd + a.x; y1 = bd + a.y; y2 = bd + bq.x; y3 = bd + bq.y;
        }
        #pragma unroll
        for (int o = 0; o < BCH; ++o) {
            const float w = s_wd[c*BCH + o];
            y0 += w*fv[o][0]; y1 += w*fv[o][1];
            y2 += w*fv[o][2]; y3 += w*fv[o][3];
        }
        f32x4 yv; yv.x = y0; yv.y = y1; yv.z = y2; yv.w = y3;
        __builtin_nontemporal_store(yv,
            reinterpret_cast<f32x4*>(reconb + (size_t)c*NN));
    }
}

extern "C" void kernel_launch(void* const* d_in, const int* in_sizes, int n_in,
                              void* d_out, int out_size, void* d_ws, size_t ws_size,
                              hipStream_t stream) {
    const float* latent   = (const float*)d_in[0];
    const float* w_flat   = (const float*)d_in[1];
    const float* b_flat   = (const float*)d_in[2];
    const float* w_deflat = (const float*)d_in[3];
    const float* b_deflat = (const float*)d_in[4];
    const float* se       = (const float*)d_in[5];
    const int*   unwalk   = (const int*)d_in[7];   // d_in[6] = walk_idx (unused)

    float* recon = (float*)d_out;
    float* flat  = (float*)d_out + (size_t)BATCH * CCH * NN;

    const size_t se_bytes = (size_t)CCH * NN * sizeof(float);
    dim3 grid(CHUNKS * BATCH);       // 736 blocks
    dim3 block(THREADS);

    if (ws_size >= se_bytes) {
        float* se_r = (float*)d_ws;
        permute_se<<<dim3((NN/4 + 255)/256, 4), dim3(256), 0, stream>>>(
            se, unwalk, b_deflat, se_r);
        flatten_k<<<grid, block, 0, stream>>>(latent, w_flat, b_flat, unwalk, flat);
        deflatten_k<1><<<grid, block, 0, stream>>>(flat, w_deflat, b_deflat,
                                                   se_r, unwalk, recon);
    } else {
        flatten_k<<<grid, block, 0, stream>>>(latent, w_flat, b_flat, unwalk, flat);
        deflatten_k<0><<<grid, block, 0, stream>>>(flat, w_deflat, b_deflat,
                                                   se, unwalk, recon);
    }
}

// Round 12
// 119.367 us; speedup vs baseline: 1.1194x; 1.1194x over previous
//
#include <hip/hip_runtime.h>

#define CCH 32
#define BCH 6
#define HH  180
#define WW  320
#define NN  (HH*WW)             // 57600
#define BATCH 32
#define RPC 8                    // rows per chunk
#define CHUNKS ((HH + RPC - 1)/RPC)   // 23 (last chunk: 4 rows)
#define THREADS 640              // 10 waves; 4 px per thread
#define NXCD 8
#define GRID_MAIN (NXCD * 3 * BATCH)  // 768: each XCD gets 3 chunk-slots x 32 b

typedef float f32x2 __attribute__((ext_vector_type(2)));
typedef float f32x4 __attribute__((ext_vector_type(4)));

// ---- kernel A: se_r[c][p] = se[c][walk-strip(p)] + b_deflat[c]
__global__ __launch_bounds__(256) void permute_se(
    const float* __restrict__ se, const int* __restrict__ unwalk,
    const float* __restrict__ b_deflat, float* __restrict__ se_r)
{
    const int p = (blockIdx.x * 256 + threadIdx.x) * 4;
    if (p >= NN) return;
    const int i  = p / WW;
    const int j  = p % WW;                      // multiple of 4
    const int nb = unwalk[(i & ~1)*WW + j];     // 2x4-block base rank
    const int n2 = nb + 2*(i & 1);
    const int c0 = blockIdx.y * (CCH/4);        // 8 channels per block.y
    #pragma unroll
    for (int cc = 0; cc < CCH/4; ++cc) {
        const int c = c0 + cc;
        const f32x2 a  = *reinterpret_cast<const f32x2*>(se + (size_t)c*NN + n2);
        const f32x2 b2 = *reinterpret_cast<const f32x2*>(se + (size_t)c*NN + n2 + 4);
        const float bd = b_deflat[c];
        f32x4 v; v.x = a.x + bd; v.y = a.y + bd; v.z = b2.x + bd; v.w = b2.y + bd;
        *reinterpret_cast<f32x4*>(se_r + (size_t)c*NN + p) = v;
    }
}

// ---- main kernel: R10 structure, but FULL unroll + VGPR headroom so ~30
// independent 16B loads stay in flight per wave (outstanding-request limit
// was the wall: unroll-8 capped in-flight bytes -> ~2-4 TB/s all session).
template<int SE_RASTER>
__global__ __launch_bounds__(THREADS, 3) void fused_flatten_deflatten(
    const float* __restrict__ latent,    // (B, C, N)
    const float* __restrict__ w_flat,    // (BCH, C)
    const float* __restrict__ b_flat,    // (BCH,)
    const float* __restrict__ w_deflat,  // (C, BCH)
    const float* __restrict__ b_deflat,  // (C,)
    const float* __restrict__ se,        // se_r (ws, bias folded) if SE_RASTER else se
    const int*   __restrict__ unwalk,    // (N,)
    float* __restrict__ recon,           // (B, C, N)
    float* __restrict__ flat_out)        // (B, BCH, N)
{
    const int g    = blockIdx.x;
    const int xcd  = g & (NXCD-1);
    const int idx  = g >> 3;
    const int r    = xcd + NXCD*(idx >> 5);   // chunk: {xcd, xcd+8, xcd+16}
    const int b    = idx & 31;                // batch (inner)
    if (r >= CHUNKS) return;

    __shared__ float s_wf[BCH*CCH];   // [o][c]
    __shared__ float s_wd[CCH*BCH];   // [c][o]
    __shared__ float s_bf[BCH];
    __shared__ float s_bd[CCH];

    const int t = threadIdx.x;
    if (t < BCH*CCH) { s_wf[t] = w_flat[t]; s_wd[t] = w_deflat[t]; }
    if (t < BCH)     s_bf[t] = b_flat[t];
    if (t < CCH)     s_bd[t] = b_deflat[t];
    __syncthreads();

    const int i  = RPC*r + t/80;       // row
    if (i >= HH) return;
    const int j  = 4*(t%80);           // col (multiple of 4)
    const int p  = i*WW + j;

    const int nb = unwalk[(i & ~1)*WW + j];
    const int n2 = nb + 2*(i & 1);

    const float* latb   = latent + (size_t)b * (CCH*NN) + p;
    float*       reconb = recon  + (size_t)b * (CCH*NN) + p;

    // ---- pass 1: flat = W_f @ latent + b_f   (FULL unroll: all 32 loads
    //      issue before the FMA chain forces the first s_waitcnt)
    float acc[BCH][4];
    #pragma unroll
    for (int o = 0; o < BCH; ++o) {
        const float bo = s_bf[o];
        acc[o][0] = bo; acc[o][1] = bo; acc[o][2] = bo; acc[o][3] = bo;
    }

    #pragma unroll
    for (int c = 0; c < CCH; ++c) {
        const f32x4 x = __builtin_nontemporal_load(
            reinterpret_cast<const f32x4*>(latb + (size_t)c*NN));
        #pragma unroll
        for (int o = 0; o < BCH; ++o) {
            const float w = s_wf[o*CCH + c];
            acc[o][0] += w*x.x; acc[o][1] += w*x.y;
            acc[o][2] += w*x.z; acc[o][3] += w*x.w;
        }
    }

    // ---- flat stores
    float* fb = flat_out + (size_t)b * (BCH*NN) + n2;
    #pragma unroll
    for (int o = 0; o < BCH; ++o) {
        f32x2 lo; lo.x = acc[o][0]; lo.y = acc[o][1];
        f32x2 hi; hi.x = acc[o][2]; hi.y = acc[o][3];
        *reinterpret_cast<f32x2*>(fb + (size_t)o*NN)     = lo;
        *reinterpret_cast<f32x2*>(fb + (size_t)o*NN + 4) = hi;
    }

    // ---- pass 2: recon = W_d @ flat + (se + b_d)   (FULL unroll)
    #pragma unroll
    for (int c = 0; c < CCH; ++c) {
        float y0, y1, y2, y3;
        if (SE_RASTER) {
            const f32x4 s4 = *reinterpret_cast<const f32x4*>(se + (size_t)c*NN + p);
            y0 = s4.x; y1 = s4.y; y2 = s4.z; y3 = s4.w;   // bias pre-folded
        } else {
            const f32x2 a  = *reinterpret_cast<const f32x2*>(se + (size_t)c*NN + n2);
            const f32x2 bq = *reinterpret_cast<const f32x2*>(se + (size_t)c*NN + n2 + 4);
            const float bd = s_bd[c];
            y0 = bd + a.x; y1 = bd + a.y; y2 = bd + bq.x; y3 = bd + bq.y;
        }
        #pragma unroll
        for (int o = 0; o < BCH; ++o) {
            const float w = s_wd[c*BCH + o];
            y0 += w*acc[o][0]; y1 += w*acc[o][1];
            y2 += w*acc[o][2]; y3 += w*acc[o][3];
        }
        f32x4 yv; yv.x = y0; yv.y = y1; yv.z = y2; yv.w = y3;
        __builtin_nontemporal_store(yv,
            reinterpret_cast<f32x4*>(reconb + (size_t)c*NN));
    }
}

extern "C" void kernel_launch(void* const* d_in, const int* in_sizes, int n_in,
                              void* d_out, int out_size, void* d_ws, size_t ws_size,
                              hipStream_t stream) {
    const float* latent   = (const float*)d_in[0];
    const float* w_flat   = (const float*)d_in[1];
    const float* b_flat   = (const float*)d_in[2];
    const float* w_deflat = (const float*)d_in[3];
    const float* b_deflat = (const float*)d_in[4];
    const float* se       = (const float*)d_in[5];
    const int*   unwalk   = (const int*)d_in[7];   // d_in[6] = walk_idx (unused)

    float* recon = (float*)d_out;
    float* flat  = (float*)d_out + (size_t)BATCH * CCH * NN;

    const size_t se_bytes = (size_t)CCH * NN * sizeof(float);
    dim3 grid(GRID_MAIN);            // 768 blocks (32 pad-exit)
    dim3 block(THREADS);

    if (ws_size >= se_bytes) {
        float* se_r = (float*)d_ws;
        permute_se<<<dim3((NN/4 + 255)/256, 4), dim3(256), 0, stream>>>(
            se, unwalk, b_deflat, se_r);
        fused_flatten_deflatten<1><<<grid, block, 0, stream>>>(
            latent, w_flat, b_flat, w_deflat, b_deflat, se_r, unwalk, recon, flat);
    } else {
        fused_flatten_deflatten<0><<<grid, block, 0, stream>>>(
            latent, w_flat, b_flat, w_deflat, b_deflat, se, unwalk, recon, flat);
    }
}